// Round 3
// baseline (1865.072 us; speedup 1.0000x reference)
//
#include <hip/hip_runtime.h>

namespace {

constexpr int T_LEN = 2048;
constexpr int B_TOT = 2048;
constexpr int H1 = 36;
constexpr int NB = 16;     // batches per wave = MFMA N
constexpr int BLOCK = 64;  // ONE wave does everything: no LDS, no barriers

typedef _Float16 f16x8 __attribute__((ext_vector_type(8)));
typedef _Float16 h16x2 __attribute__((ext_vector_type(2)));
typedef float f32x4 __attribute__((ext_vector_type(4)));

__device__ __forceinline__ float fdot2(float wb, float hb, float acc) {
#if __has_builtin(__builtin_amdgcn_fdot2)
  return __builtin_amdgcn_fdot2(__builtin_bit_cast(h16x2, wb),
                                __builtin_bit_cast(h16x2, hb), acc, false);
#else
  float d;
  asm("v_dot2_f32_f16 %0, %1, %2, %3" : "=v"(d) : "v"(wb), "v"(hb), "0"(acc));
  return d;
#endif
}
__device__ __forceinline__ float pack2h(float a, float b) {
  h16x2 t = {(_Float16)a, (_Float16)b};
  return __builtin_bit_cast(float, t);
}
__device__ __forceinline__ float pkrelu(float v) {  // packed f16 max(x,0)
  float r;
  asm("v_pk_max_f16 %0, %1, %2" : "=v"(r) : "v"(v), "v"(0.f));
  return r;
}
__device__ __forceinline__ float fexp2(float x) { return __builtin_amdgcn_exp2f(x); }
__device__ __forceinline__ float frcp(float x) { return __builtin_amdgcn_rcpf(x); }

// In-wave butterfly helpers (crossbar only, no LDS storage, no barrier).
__device__ __forceinline__ float xl16(float v) {  // lane ^ 16
  return __builtin_bit_cast(
      float, __builtin_amdgcn_ds_swizzle(__builtin_bit_cast(int, v), 0x401F));
}
__device__ __forceinline__ float xl32(float v, int lane) {  // lane ^ 32
  return __builtin_bit_cast(
      float, __builtin_amdgcn_ds_bpermute((lane ^ 32) << 2,
                                          __builtin_bit_cast(int, v)));
}

// LSTM cell with gate scales folded into the WEIGHTS:
//   pi,pf,po arrive pre-multiplied by -log2(e); pg by -2*log2(e).
//   cS tracks -2*log2(e)*c, so tanh(c) = 2*rcp(1+exp2(cS)) - 1.
// Per unit: 5 exp2 + 5 rcp + 10 VALU (no explicit scale muls).
__device__ __forceinline__ float lstm_unit(float pi, float pf, float pg, float po,
                                           float& cS) {
  const float I = frcp(1.f + fexp2(pi));
  const float F = frcp(1.f + fexp2(pf));
  const float O = frcp(1.f + fexp2(po));
  const float rG = frcp(1.f + fexp2(pg));
  const float Gs = fmaf(rG, -5.77078016f, 2.88539008f);  // -2log2e * tanh(g)
  cS = fmaf(F, cS, I * Gs);
  const float rC = frcp(1.f + fexp2(cS));
  return fmaf(rC, O + O, -O);  // O * tanh(c)
}

__global__ __launch_bounds__(BLOCK) void lstm2_kernel(
    const float* __restrict__ x, const float* __restrict__ Wih1,
    const float* __restrict__ Whh1, const float* __restrict__ bih1,
    const float* __restrict__ bhh1, const float* __restrict__ Wih2,
    const float* __restrict__ Whh2, const float* __restrict__ bih2,
    const float* __restrict__ bhh2, float* __restrict__ out)
{
  const int lane = threadIdx.x & 63;
  const int m = lane & 15;   // batch column (MFMA N / A-row / C-col)
  const int q = lane >> 4;   // k-group (A,B) / C row-group
  const int g0 = blockIdx.x * NB;

  // ---- Unit-to-lane mapping (the whole trick) ----
  // C-row 4q+r of tile t  <->  (unit U(q,t), gate r), with
  //   U(q,t) = 8q + t  (t=0..7),  U(q,8) = 32 + q.
  // => after activation, lane (q,m) holds h[8q+0..7] and h[32+q], which is
  //    EXACTLY the B operand this lane must supply next step:
  //    B0[j] = h[8q+j],  B1[j=0] = h[32+q].  Zero redistribution.
  // B1's spare k-slots carry x (hi/lo f16 split) and bias (hi/lo in A1):
  //    k=1: x_hi, k=2: x_lo (A1 cols = Wih1), k=3,4: 1.0 (A1 cols = b_hi,b_lo).
  const int ga = m & 3;   // gate of this lane's A-rows
  const int qa = m >> 2;  // unit-slot of this lane's A-rows
  const float sga = (ga == 2) ? -2.88539008f : -1.44269504f;  // fold gate scale

  f16x8 A0[9], A1[9];
#pragma unroll
  for (int t = 0; t < 9; ++t) {
    const int uA = (t < 8) ? (8 * qa + t) : (32 + qa);
    const int row = ga * H1 + uA;  // Whh1/Wih1 global row (i,f,g,o blocks)
#pragma unroll
    for (int j = 0; j < 8; ++j)
      A0[t][j] = (_Float16)(sga * Whh1[row * H1 + q * 8 + j]);  // k=unit 0..31
#pragma unroll
    for (int j = 0; j < 8; ++j) A1[t][j] = (_Float16)0.f;
    A1[t][0] = (_Float16)(sga * Whh1[row * H1 + 32 + q]);  // k=8q -> unit 32+q
    if (q == 0) {  // only k=1..4 columns exist (q=0's k-group)
      const _Float16 wih = (_Float16)(sga * Wih1[row]);
      A1[t][1] = wih;  // * x_hi
      A1[t][2] = wih;  // * x_lo
      const float bb = sga * (bih1[row] + bhh1[row]);
      const _Float16 bh = (_Float16)bb;
      A1[t][3] = bh;                           // * 1.0
      A1[t][4] = (_Float16)(bb - (float)bh);   // * 1.0 (bias residual)
    }
  }

  // ---- layer-2 weights: per lane, its 9 units' columns, all 4 gates ----
  float w2p[4][4], w2s[4], whg2[4], b2s[4];
#pragma unroll
  for (int g2 = 0; g2 < 4; ++g2) {
    const float s2 = (g2 == 2) ? -2.88539008f : -1.44269504f;
    const float* wr = Wih2 + g2 * H1;
#pragma unroll
    for (int d = 0; d < 4; ++d)
      w2p[g2][d] = pack2h(s2 * wr[8 * q + 2 * d], s2 * wr[8 * q + 2 * d + 1]);
    w2s[g2] = s2 * wr[32 + q];
    whg2[g2] = s2 * Whh2[g2];
    b2s[g2] = s2 * (bih2[g2] + bhh2[g2]);
  }

  float cS[9];
#pragma unroll
  for (int t = 0; t < 9; ++t) cS[t] = 0.f;
  float c2S = 0.f, h2 = 0.f;

  f16x8 B0, B1;
#pragma unroll
  for (int j = 0; j < 8; ++j) { B0[j] = (_Float16)0.f; B1[j] = (_Float16)0.f; }
  B1[3] = (_Float16)1.f;  // bias_hi slot
  B1[4] = (_Float16)1.f;  // bias_lo slot

  const float* xc = x + (size_t)(g0 + m) * T_LEN;
  float* outp = out + (size_t)(g0 + m) * T_LEN;
  float4 qx = *(const float4*)xc;
  float4 ov = make_float4(0.f, 0.f, 0.f, 0.f);

  const f32x4 z4 = {0.f, 0.f, 0.f, 0.f};

  auto step = [&](int i, float xv, int s) {
    // x into B1 (hi/lo f16 split keeps ~22 bits of x)
    const _Float16 xh = (_Float16)xv;
    B1[1] = xh;
    B1[2] = (_Float16)(xv - (float)xh);

    f32x4 cc[9];
#pragma unroll
    for (int t = 0; t < 9; ++t)
      cc[t] = __builtin_amdgcn_mfma_f32_16x16x32_f16(A0[t], B0, z4, 0, 0, 0);
#pragma unroll
    for (int t = 0; t < 9; ++t)
      cc[t] = __builtin_amdgcn_mfma_f32_16x16x32_f16(A1[t], B1, cc[t], 0, 0, 0);

    float h[9];
#pragma unroll
    for (int t = 0; t < 9; ++t)
      h[t] = lstm_unit(cc[t][0], cc[t][1], cc[t][2], cc[t][3], cS[t]);

    // repack next-step B operands (lane-local by construction)
#pragma unroll
    for (int t = 0; t < 8; ++t) B0[t] = (_Float16)h[t];
    B1[0] = (_Float16)h[8];

    // ---- layer 2: uses relu(h) of THIS step; all lanes redundantly ----
    const f32x4 b0d = __builtin_bit_cast(f32x4, B0);
    float pk[4];
#pragma unroll
    for (int d = 0; d < 4; ++d) pk[d] = pkrelu(b0d[d]);
    const float rl8 = fmaxf(h[8], 0.f);
    float pre[4];
#pragma unroll
    for (int g2 = 0; g2 < 4; ++g2) {
      float aE = fdot2(w2p[g2][0], pk[0], rl8 * w2s[g2]);
      float aO = fdot2(w2p[g2][1], pk[1], 0.f);
      aE = fdot2(w2p[g2][2], pk[2], aE);
      aO = fdot2(w2p[g2][3], pk[3], aO);
      float p = aE + aO;
      p += xl16(p);        // + lane^16 partial
      p += xl32(p, lane);  // + lane^32 partial -> full 36-unit dot in all lanes
      pre[g2] = fmaf(h2, whg2[g2], p + b2s[g2]);
    }
    h2 = lstm_unit(pre[0], pre[1], pre[2], pre[3], c2S);

    if (s == 0) ov.x = h2;
    else if (s == 1) ov.y = h2;
    else if (s == 2) ov.z = h2;
    else {
      ov.w = h2;
      if (q == 0) *(float4*)(outp + (i - 3)) = ov;  // out[i-3..i]
    }
  };

  for (int i0 = 0; i0 < T_LEN; i0 += 4) {
    const int tn = (i0 + 4 < T_LEN) ? (i0 + 4) : (T_LEN - 4);
    const float4 qn = *(const float4*)(xc + tn);  // prefetch (dup at tail, unused)
    step(i0 + 0, qx.x, 0);
    step(i0 + 1, qx.y, 1);
    step(i0 + 2, qx.z, 2);
    step(i0 + 3, qx.w, 3);
    qx = qn;
  }
}

}  // namespace

extern "C" void kernel_launch(void* const* d_in, const int* in_sizes, int n_in,
                              void* d_out, int out_size, void* d_ws, size_t ws_size,
                              hipStream_t stream) {
  const float* x    = (const float*)d_in[0];
  const float* Wih1 = (const float*)d_in[1];
  const float* Whh1 = (const float*)d_in[2];
  const float* bih1 = (const float*)d_in[3];
  const float* bhh1 = (const float*)d_in[4];
  const float* Wih2 = (const float*)d_in[5];
  const float* Whh2 = (const float*)d_in[6];
  const float* bih2 = (const float*)d_in[7];
  const float* bhh2 = (const float*)d_in[8];
  float* out = (float*)d_out;

  dim3 grid(B_TOT / NB);  // 128 independent waves, one per 16-batch group
  dim3 block(BLOCK);      // 64 threads = 1 wave: no LDS, no barriers
  hipLaunchKernelGGL(lstm2_kernel, grid, block, 0, stream,
                     x, Wih1, Whh1, bih1, bhh1, Wih2, Whh2, bih2, bhh2, out);
}

// Round 4
// 791.879 us; speedup vs baseline: 2.3552x; 2.3552x over previous
//
#include <hip/hip_runtime.h>

namespace {

constexpr int T_LEN = 2048;
constexpr int B_TOT = 2048;
constexpr int H1 = 36;
constexpr int NB = 16;      // batches per block = MFMA N
constexpr int BLOCK = 640;  // 9 A-waves (M-tiles) + 1 L2 wave
constexpr int RS = 72;      // h row stride in halves (144B, 16B-aligned)

typedef _Float16 f16x8 __attribute__((ext_vector_type(8)));
typedef _Float16 h16x2 __attribute__((ext_vector_type(2)));
typedef float f32x4 __attribute__((ext_vector_type(4)));

__device__ __forceinline__ float fdot2(float wb, float hb, float acc) {
#if __has_builtin(__builtin_amdgcn_fdot2)
  return __builtin_amdgcn_fdot2(__builtin_bit_cast(h16x2, wb),
                                __builtin_bit_cast(h16x2, hb), acc, false);
#else
  float d;
  asm("v_dot2_f32_f16 %0, %1, %2, %3" : "=v"(d) : "v"(wb), "v"(hb), "0"(acc));
  return d;
#endif
}
__device__ __forceinline__ float pack2h(float a, float b) {
  h16x2 t = {(_Float16)a, (_Float16)b};
  return __builtin_bit_cast(float, t);
}
// Quad-broadcast via DPP quad_perm (VALU pipe, off LDS).
template <int CTRL>
__device__ __forceinline__ float qb(float v) {
  return __builtin_bit_cast(
      float, __builtin_amdgcn_update_dpp(0, __builtin_bit_cast(int, v), CTRL,
                                         0xf, 0xf, true));
}
__device__ __forceinline__ float fexp2(float x) { return __builtin_amdgcn_exp2f(x); }
__device__ __forceinline__ float frcp(float x) { return __builtin_amdgcn_rcpf(x); }

// Scaled-gate LSTM cell (round-3-verified numerics): pre-activations arrive
// pre-multiplied by -log2e (i,f,o) / -2log2e (g); cS tracks -2log2e*c.
// 10 trans + ~10 VALU, no scale muls.
__device__ __forceinline__ float lstm_unit(float pi, float pf, float pg, float po,
                                           float& cS) {
  const float I = frcp(1.f + fexp2(pi));
  const float F = frcp(1.f + fexp2(pf));
  const float O = frcp(1.f + fexp2(po));
  const float rG = frcp(1.f + fexp2(pg));
  const float Gs = fmaf(rG, -5.77078016f, 2.88539008f);  // -2log2e * tanh(g)
  cS = fmaf(F, cS, I * Gs);
  const float rC = frcp(1.f + fexp2(cS));
  return fmaf(rC, O + O, -O);  // O * tanh(c)
}

// Raw barrier: producer-side lgkmcnt(0) only (no vmcnt/expcnt drain).
__device__ __forceinline__ void step_sync() {
  asm volatile("s_waitcnt lgkmcnt(0)" ::: "memory");
  __builtin_amdgcn_s_barrier();
  __builtin_amdgcn_sched_barrier(0);
  asm volatile("" ::: "memory");
}

__global__ __launch_bounds__(BLOCK) void lstm2_kernel(
    const float* __restrict__ x, const float* __restrict__ Wih1,
    const float* __restrict__ Whh1, const float* __restrict__ bih1,
    const float* __restrict__ bhh1, const float* __restrict__ Wih2,
    const float* __restrict__ Whh2, const float* __restrict__ bih2,
    const float* __restrict__ bhh2, float* __restrict__ out)
{
  // lds[buf][plane][batch][k]: plane0 = h(f16) + B1-stuffing
  //   (k=36: x_hi, 37: x_lo, 38,39: 1.0 for bias cols; 40..71 stay zero),
  // plane1 = relu(h) for the L2 wave's dots.
  __shared__ __align__(16) _Float16 lds[2][2][NB][RS];

  const int tid = threadIdx.x;
  const int wid = tid >> 6;
  const int lane = tid & 63;
  const int m = lane & 15;   // A-row group / B,C: batch col
  const int q = lane >> 4;   // k-group / C row-group
  const int g0 = blockIdx.x * NB;
  const bool isA = wid < 9;

  for (int i = tid; i < 2 * 2 * NB * RS; i += BLOCK)
    ((_Float16*)lds)[i] = (_Float16)0.f;
  __syncthreads();
  if (tid < NB) {  // bias columns (both bufs) + x_0 into buf1
    lds[0][0][tid][38] = (_Float16)1.f;
    lds[0][0][tid][39] = (_Float16)1.f;
    lds[1][0][tid][38] = (_Float16)1.f;
    lds[1][0][tid][39] = (_Float16)1.f;
    const float x0 = x[(size_t)(g0 + tid) * T_LEN];
    const _Float16 xh0 = (_Float16)x0;
    lds[1][0][tid][36] = xh0;
    lds[1][0][tid][37] = (_Float16)(x0 - (float)xh0);
  }
  __syncthreads();

  // ---- A-wave setup: tile wid = units wid*4..+3, all 4 gates, 16 batches.
  // A-row r_: gate = r_&3, uloc = r_>>2, orig row = gate*H1 + (u0+uloc).
  // All weights pre-scaled by the gate's -log2e / -2log2e factor.
  // A1 (k=32..39, held by q==0 lanes): [Whh tail 32..35 | Wih | Wih | b_hi | b_lo]
  f16x8 A0 = {}, A1 = {};
  float c1 = 0.f;
  int ku = 0;
  if (isA) {
    const int u0 = wid * 4;
    ku = u0 + q;  // this lane's unit (C rows 4q+r = unit u0+q, gate r)
    const float sga = ((m & 3) == 2) ? -2.88539008f : -1.44269504f;
    const int ra = (m & 3) * H1 + (u0 + (m >> 2));
#pragma unroll
    for (int j = 0; j < 8; ++j)
      A0[j] = (_Float16)(sga * Whh1[ra * H1 + q * 8 + j]);  // k=q*8+j < 32
#pragma unroll
    for (int j = 0; j < 8; ++j) A1[j] = (_Float16)0.f;
    if (q == 0) {
#pragma unroll
      for (int j = 0; j < 4; ++j)
        A1[j] = (_Float16)(sga * Whh1[ra * H1 + 32 + j]);  // tail k=32..35
      const _Float16 wih = (_Float16)(sga * Wih1[ra]);
      A1[4] = wih;  // * x_hi
      A1[5] = wih;  // * x_lo  -> (x_hi+x_lo)*wih = x*wih
      const float bb = sga * (bih1[ra] + bhh1[ra]);
      const _Float16 bh = (_Float16)bb;
      A1[6] = bh;                           // * 1.0
      A1[7] = (_Float16)(bb - (float)bh);   // * 1.0 (bias residual)
    }
  }

  // ---- wave 8 doubles as the x-feeder (writes x_{i+1} into buf[wb]) ----
  const float* xc = nullptr;
  float4 qx = make_float4(0.f, 0.f, 0.f, 0.f);
  if (wid == 8) {
    xc = x + (size_t)(g0 + m) * T_LEN;
    qx = *(const float4*)xc;  // x[0..3]
  }

  // ---- L2 wave (wid==9): lane = batch*4 + gate; weights pre-scaled ----
  const int lb = lane >> 2, lg = lane & 3;
  float w2[18];
  float whg = 0.f, b2 = 0.f, c2S = 0.f, h2 = 0.f;
  float* outp = nullptr;
#pragma unroll
  for (int k = 0; k < 18; ++k) w2[k] = 0.f;
  if (wid == 9) {
    const float s2 = (lg == 2) ? -2.88539008f : -1.44269504f;
    const float* wr = Wih2 + lg * H1;
#pragma unroll
    for (int k = 0; k < 18; ++k)
      w2[k] = pack2h(s2 * wr[2 * k], s2 * wr[2 * k + 1]);
    whg = s2 * Whh2[lg];
    b2 = s2 * (bih2[lg] + bhh2[lg]);
    outp = out + (size_t)(g0 + lb) * T_LEN;
  }

  float4 ov = make_float4(0.f, 0.f, 0.f, 0.f);
  const f32x4 z4 = {0.f, 0.f, 0.f, 0.f};

  // Round i: A-waves compute h_i from buf[ib] (h_{i-1}, x_i); wave8 writes
  // x_{i+1} into buf[wb]; L2 computes out[i-1]. One raw barrier per round.
  auto step = [&](int i, int s, float xw) {
    const int ib = (s + 1) & 1;
    const int wb = s & 1;
    if (isA) {
      const f16x8 B0 = *(const f16x8*)&lds[ib][0][m][q * 8];
      const f16x8 B1 = *(const f16x8*)&lds[ib][0][m][32 + q * 8];
      f32x4 cc = __builtin_amdgcn_mfma_f32_16x16x32_f16(A0, B0, z4, 0, 0, 0);
      cc = __builtin_amdgcn_mfma_f32_16x16x32_f16(A1, B1, cc, 0, 0, 0);
      const float h = lstm_unit(cc[0], cc[1], cc[2], cc[3], c1);
      const _Float16 hh = (_Float16)h;
      lds[wb][0][m][ku] = hh;
      lds[wb][1][m][ku] = (hh > (_Float16)0.f) ? hh : (_Float16)0.f;
      if (wid == 8 && q == 0) {  // feed x_{i+1} for next round
        const _Float16 xh = (_Float16)xw;
        h16x2 xp = {xh, (_Float16)(xw - (float)xh)};
        *(h16x2*)&lds[wb][0][m][36] = xp;
      }
    } else if (i > 0) {
      const char* rp = (const char*)&lds[ib][1][lb][0];  // relu(h_{i-1})
      const float4 r0 = *(const float4*)rp;
      const float4 r1 = *(const float4*)(rp + 16);
      const float4 r2 = *(const float4*)(rp + 32);
      const float4 r3 = *(const float4*)(rp + 48);
      const float2 r4 = *(const float2*)(rp + 64);
      const float f[18] = {r0.x, r0.y, r0.z, r0.w, r1.x, r1.y, r1.z, r1.w,
                           r2.x, r2.y, r2.z, r2.w, r3.x, r3.y, r3.z, r3.w,
                           r4.x, r4.y};
      // 4 accumulators: dot dep-chain depth 5; seed with h2/bias term.
      float a0 = fdot2(w2[0], f[0], fmaf(h2, whg, b2));
      float a1 = fdot2(w2[1], f[1], 0.f);
      float a2 = fdot2(w2[2], f[2], 0.f);
      float a3 = fdot2(w2[3], f[3], 0.f);
#pragma unroll
      for (int k = 4; k < 16; k += 4) {
        a0 = fdot2(w2[k], f[k], a0);
        a1 = fdot2(w2[k + 1], f[k + 1], a1);
        a2 = fdot2(w2[k + 2], f[k + 2], a2);
        a3 = fdot2(w2[k + 3], f[k + 3], a3);
      }
      a0 = fdot2(w2[16], f[16], a0);
      a1 = fdot2(w2[17], f[17], a1);
      const float pre = (a0 + a2) + (a1 + a3);  // scaled gate lg pre-act
      const float pI = qb<0x00>(pre);
      const float pF = qb<0x55>(pre);
      const float pG = qb<0xAA>(pre);
      const float pO = qb<0xFF>(pre);
      h2 = lstm_unit(pI, pF, pG, pO, c2S);  // = out[i-1], replicated in quad
      if (s == 1) ov.x = h2;
      else if (s == 2) ov.y = h2;
      else if (s == 3) ov.z = h2;
      else {
        ov.w = h2;
        if (lg == 0) *(float4*)(outp + (i - 4)) = ov;  // out[i-4..i-1]
      }
    }
    step_sync();
  };

  for (int i0 = 0; i0 < T_LEN; i0 += 4) {
    float4 qn = qx;
    if (wid == 8) {  // prefetch next x quad (clamped at tail)
      const int tn = (i0 + 4 < T_LEN) ? (i0 + 4) : (T_LEN - 4);
      qn = *(const float4*)(xc + tn);
    }
    step(i0 + 0, 0, qx.y);  // write x[i0+1]
    step(i0 + 1, 1, qx.z);  // write x[i0+2]
    step(i0 + 2, 2, qx.w);  // write x[i0+3]
    step(i0 + 3, 3, qn.x);  // write x[i0+4]
    qx = qn;
  }
  // Final round: A computes discarded h_2048 (x slot holds stale-but-finite
  // data); L2 emits out[2047] and stores out[2044..2047].
  step(T_LEN, 0, qx.y);
}

}  // namespace

extern "C" void kernel_launch(void* const* d_in, const int* in_sizes, int n_in,
                              void* d_out, int out_size, void* d_ws, size_t ws_size,
                              hipStream_t stream) {
  const float* x    = (const float*)d_in[0];
  const float* Wih1 = (const float*)d_in[1];
  const float* Whh1 = (const float*)d_in[2];
  const float* bih1 = (const float*)d_in[3];
  const float* bhh1 = (const float*)d_in[4];
  const float* Wih2 = (const float*)d_in[5];
  const float* Whh2 = (const float*)d_in[6];
  const float* bih2 = (const float*)d_in[7];
  const float* bhh2 = (const float*)d_in[8];
  float* out = (float*)d_out;

  dim3 grid(B_TOT / NB);  // 128 blocks x 16 batches
  dim3 block(BLOCK);      // 9 MFMA waves + 1 L2 wave
  hipLaunchKernelGGL(lstm2_kernel, grid, block, 0, stream,
                     x, Wih1, Whh1, bih1, bhh1, Wih2, Whh2, bih2, bhh2, out);
}

// Round 5
// 788.927 us; speedup vs baseline: 2.3641x; 1.0037x over previous
//
#include <hip/hip_runtime.h>

namespace {

constexpr int T_LEN = 2048;
constexpr int B_TOT = 2048;
constexpr int H1 = 36;
constexpr int NB = 16;      // batches per block = MFMA N
constexpr int BLOCK = 640;  // 9 A-waves (M-tiles) + 1 L2 wave
constexpr int RS = 72;      // h row stride in halves (144B, 16B-aligned)

typedef _Float16 f16x8 __attribute__((ext_vector_type(8)));
typedef _Float16 h16x2 __attribute__((ext_vector_type(2)));
typedef float f32x4 __attribute__((ext_vector_type(4)));

__device__ __forceinline__ float fdot2(float wb, float hb, float acc) {
#if __has_builtin(__builtin_amdgcn_fdot2)
  return __builtin_amdgcn_fdot2(__builtin_bit_cast(h16x2, wb),
                                __builtin_bit_cast(h16x2, hb), acc, false);
#else
  float d;
  asm("v_dot2_f32_f16 %0, %1, %2, %3" : "=v"(d) : "v"(wb), "v"(hb), "0"(acc));
  return d;
#endif
}
__device__ __forceinline__ float pack2h(float a, float b) {
  h16x2 t = {(_Float16)a, (_Float16)b};
  return __builtin_bit_cast(float, t);
}
// Quad-broadcast via DPP quad_perm (VALU pipe, off LDS).
template <int CTRL>
__device__ __forceinline__ float qb(float v) {
  return __builtin_bit_cast(
      float, __builtin_amdgcn_update_dpp(0, __builtin_bit_cast(int, v), CTRL,
                                         0xf, 0xf, true));
}
__device__ __forceinline__ float fexp2(float x) { return __builtin_amdgcn_exp2f(x); }
__device__ __forceinline__ float frcp(float x) { return __builtin_amdgcn_rcpf(x); }

// Scaled-gate LSTM cell, 8-trans form (was 10): pre-activations arrive
// pre-multiplied by -log2e (i,f,o) / -2log2e (g); cS tracks -2log2e*c.
//   I*tanh(g) = -2log2e*(1-Eg) / [(1+Ei)(1+Eg)]   -> one rcp for both
//   O*tanh(c) = (1-Ec) / [(1+Eo)(1+Ec)]           -> one rcp for both
// Range-safe here: |preact| <~ 6 -> E <= 2^9, products <= 2^18.
__device__ __forceinline__ float lstm_unit(float pi, float pf, float pg, float po,
                                           float& cS) {
  const float Ei = fexp2(pi);
  const float Ef = fexp2(pf);
  const float Eg = fexp2(pg);
  const float Eo = fexp2(po);
  const float F = frcp(1.f + Ef);
  const float Rig = frcp((1.f + Ei) * (1.f + Eg));
  const float numg = fmaf(Eg, 2.88539008f, -2.88539008f);  // -2log2e*(1-Eg)
  cS = fmaf(F, cS, numg * Rig);
  const float Ec = fexp2(cS);
  const float Roc = frcp((1.f + Eo) * (1.f + Ec));
  return (1.f - Ec) * Roc;  // O * tanh(c)
}

// Raw barrier: producer-side lgkmcnt(0) only (no vmcnt/expcnt drain).
__device__ __forceinline__ void step_sync() {
  asm volatile("s_waitcnt lgkmcnt(0)" ::: "memory");
  __builtin_amdgcn_s_barrier();
  __builtin_amdgcn_sched_barrier(0);
  asm volatile("" ::: "memory");
}

__global__ __launch_bounds__(BLOCK) void lstm2_kernel(
    const float* __restrict__ x, const float* __restrict__ Wih1,
    const float* __restrict__ Whh1, const float* __restrict__ bih1,
    const float* __restrict__ bhh1, const float* __restrict__ Wih2,
    const float* __restrict__ Whh2, const float* __restrict__ bih2,
    const float* __restrict__ bhh2, float* __restrict__ out)
{
  // lds[buf][plane][batch][k]: plane0 = h(f16) + B1-stuffing
  //   (k=36: x_hi, 37: x_lo, 38,39: 1.0 for bias cols; 40..71 stay zero),
  // plane1 = relu(h) for the L2 wave's dots.
  __shared__ __align__(16) _Float16 lds[2][2][NB][RS];

  const int tid = threadIdx.x;
  const int wid = tid >> 6;
  const int lane = tid & 63;
  const int m = lane & 15;   // A-row group / B,C: batch col
  const int q = lane >> 4;   // k-group / C row-group
  const int g0 = blockIdx.x * NB;
  const bool isA = wid < 9;

  for (int i = tid; i < 2 * 2 * NB * RS; i += BLOCK)
    ((_Float16*)lds)[i] = (_Float16)0.f;
  __syncthreads();
  if (tid < NB) {  // bias columns (both bufs) + x_0 into buf1
    lds[0][0][tid][38] = (_Float16)1.f;
    lds[0][0][tid][39] = (_Float16)1.f;
    lds[1][0][tid][38] = (_Float16)1.f;
    lds[1][0][tid][39] = (_Float16)1.f;
    const float x0 = x[(size_t)(g0 + tid) * T_LEN];
    const _Float16 xh0 = (_Float16)x0;
    lds[1][0][tid][36] = xh0;
    lds[1][0][tid][37] = (_Float16)(x0 - (float)xh0);
  }
  __syncthreads();

  // ---- A-wave setup: tile wid = units wid*4..+3, all 4 gates, 16 batches.
  // A-row r_: gate = r_&3, uloc = r_>>2, orig row = gate*H1 + (u0+uloc).
  // All weights pre-scaled by the gate's -log2e / -2log2e factor.
  // A1 (k=32..39, held by q==0 lanes): [Whh tail 32..35 | Wih | Wih | b_hi | b_lo]
  f16x8 A0 = {}, A1 = {};
  float c1 = 0.f;
  int ku = 0;
  if (isA) {
    const int u0 = wid * 4;
    ku = u0 + q;  // this lane's unit (C rows 4q+r = unit u0+q, gate r)
    const float sga = ((m & 3) == 2) ? -2.88539008f : -1.44269504f;
    const int ra = (m & 3) * H1 + (u0 + (m >> 2));
#pragma unroll
    for (int j = 0; j < 8; ++j)
      A0[j] = (_Float16)(sga * Whh1[ra * H1 + q * 8 + j]);  // k=q*8+j < 32
#pragma unroll
    for (int j = 0; j < 8; ++j) A1[j] = (_Float16)0.f;
    if (q == 0) {
#pragma unroll
      for (int j = 0; j < 4; ++j)
        A1[j] = (_Float16)(sga * Whh1[ra * H1 + 32 + j]);  // tail k=32..35
      const _Float16 wih = (_Float16)(sga * Wih1[ra]);
      A1[4] = wih;  // * x_hi
      A1[5] = wih;  // * x_lo  -> (x_hi+x_lo)*wih = x*wih
      const float bb = sga * (bih1[ra] + bhh1[ra]);
      const _Float16 bh = (_Float16)bb;
      A1[6] = bh;                           // * 1.0
      A1[7] = (_Float16)(bb - (float)bh);   // * 1.0 (bias residual)
    }
  }

  // ---- wave 8 doubles as the x-feeder (writes x_{i+1} into buf[wb]) ----
  const float* xc = nullptr;
  float4 qx = make_float4(0.f, 0.f, 0.f, 0.f);
  if (wid == 8) {
    xc = x + (size_t)(g0 + m) * T_LEN;
    qx = *(const float4*)xc;  // x[0..3]
  }

  // ---- L2 wave (wid==9): lane = batch*4 + gate; weights pre-scaled ----
  const int lb = lane >> 2, lg = lane & 3;
  float w2[18];
  float whg = 0.f, b2 = 0.f, c2S = 0.f, h2 = 0.f;
  float* outp = nullptr;
#pragma unroll
  for (int k = 0; k < 18; ++k) w2[k] = 0.f;
  if (wid == 9) {
    const float s2 = (lg == 2) ? -2.88539008f : -1.44269504f;
    const float* wr = Wih2 + lg * H1;
#pragma unroll
    for (int k = 0; k < 18; ++k)
      w2[k] = pack2h(s2 * wr[2 * k], s2 * wr[2 * k + 1]);
    whg = s2 * Whh2[lg];
    b2 = s2 * (bih2[lg] + bhh2[lg]);
    outp = out + (size_t)(g0 + lb) * T_LEN;
  }

  float4 ov = make_float4(0.f, 0.f, 0.f, 0.f);
  const f32x4 z4 = {0.f, 0.f, 0.f, 0.f};

  // Round i: A-waves compute h_i from buf[ib] (h_{i-1}, x_i); wave8 writes
  // x_{i+1} into buf[wb]; L2 computes out[i-1]. One raw barrier per round.
  auto step = [&](int i, int s, float xw) {
    const int ib = (s + 1) & 1;
    const int wb = s & 1;
    if (isA) {
      const f16x8 B0 = *(const f16x8*)&lds[ib][0][m][q * 8];
      const f16x8 B1 = *(const f16x8*)&lds[ib][0][m][32 + q * 8];
      // Independent MFMAs (both seed 0), merged by VALU: one MFMA completion
      // latency off the serial chain vs the chained form.
      const f32x4 cc1 = __builtin_amdgcn_mfma_f32_16x16x32_f16(A0, B0, z4, 0, 0, 0);
      const f32x4 cc2 = __builtin_amdgcn_mfma_f32_16x16x32_f16(A1, B1, z4, 0, 0, 0);
      const float h = lstm_unit(cc1[0] + cc2[0], cc1[1] + cc2[1],
                                cc1[2] + cc2[2], cc1[3] + cc2[3], c1);
      const _Float16 hh = (_Float16)h;
      lds[wb][0][m][ku] = hh;
      lds[wb][1][m][ku] = (hh > (_Float16)0.f) ? hh : (_Float16)0.f;
      if (wid == 8 && q == 0) {  // feed x_{i+1} for next round
        const _Float16 xh = (_Float16)xw;
        h16x2 xp = {xh, (_Float16)(xw - (float)xh)};
        *(h16x2*)&lds[wb][0][m][36] = xp;
      }
    } else if (i > 0) {
      const char* rp = (const char*)&lds[ib][1][lb][0];  // relu(h_{i-1})
      const float4 r0 = *(const float4*)rp;
      const float4 r1 = *(const float4*)(rp + 16);
      const float4 r2 = *(const float4*)(rp + 32);
      const float4 r3 = *(const float4*)(rp + 48);
      const float2 r4 = *(const float2*)(rp + 64);
      const float f[18] = {r0.x, r0.y, r0.z, r0.w, r1.x, r1.y, r1.z, r1.w,
                           r2.x, r2.y, r2.z, r2.w, r3.x, r3.y, r3.z, r3.w,
                           r4.x, r4.y};
      // 4 accumulators: dot dep-chain depth 5; seed with h2/bias term.
      float a0 = fdot2(w2[0], f[0], fmaf(h2, whg, b2));
      float a1 = fdot2(w2[1], f[1], 0.f);
      float a2 = fdot2(w2[2], f[2], 0.f);
      float a3 = fdot2(w2[3], f[3], 0.f);
#pragma unroll
      for (int k = 4; k < 16; k += 4) {
        a0 = fdot2(w2[k], f[k], a0);
        a1 = fdot2(w2[k + 1], f[k + 1], a1);
        a2 = fdot2(w2[k + 2], f[k + 2], a2);
        a3 = fdot2(w2[k + 3], f[k + 3], a3);
      }
      a0 = fdot2(w2[16], f[16], a0);
      a1 = fdot2(w2[17], f[17], a1);
      const float pre = (a0 + a2) + (a1 + a3);  // scaled gate lg pre-act
      const float pI = qb<0x00>(pre);
      const float pF = qb<0x55>(pre);
      const float pG = qb<0xAA>(pre);
      const float pO = qb<0xFF>(pre);
      h2 = lstm_unit(pI, pF, pG, pO, c2S);  // = out[i-1], replicated in quad
      if (s == 1) ov.x = h2;
      else if (s == 2) ov.y = h2;
      else if (s == 3) ov.z = h2;
      else {
        ov.w = h2;
        if (lg == 0) *(float4*)(outp + (i - 4)) = ov;  // out[i-4..i-1]
      }
    }
    step_sync();
  };

  for (int i0 = 0; i0 < T_LEN; i0 += 4) {
    float4 qn = qx;
    if (wid == 8) {  // prefetch next x quad (clamped at tail)
      const int tn = (i0 + 4 < T_LEN) ? (i0 + 4) : (T_LEN - 4);
      qn = *(const float4*)(xc + tn);
    }
    step(i0 + 0, 0, qx.y);  // write x[i0+1]
    step(i0 + 1, 1, qx.z);  // write x[i0+2]
    step(i0 + 2, 2, qx.w);  // write x[i0+3]
    step(i0 + 3, 3, qn.x);  // write x[i0+4]
    qx = qn;
  }
  // Final round: A computes discarded h_2048 (x slot holds stale-but-finite
  // data); L2 emits out[2047] and stores out[2044..2047].
  step(T_LEN, 0, qx.y);
}

}  // namespace

extern "C" void kernel_launch(void* const* d_in, const int* in_sizes, int n_in,
                              void* d_out, int out_size, void* d_ws, size_t ws_size,
                              hipStream_t stream) {
  const float* x    = (const float*)d_in[0];
  const float* Wih1 = (const float*)d_in[1];
  const float* Whh1 = (const float*)d_in[2];
  const float* bih1 = (const float*)d_in[3];
  const float* bhh1 = (const float*)d_in[4];
  const float* Wih2 = (const float*)d_in[5];
  const float* Whh2 = (const float*)d_in[6];
  const float* bih2 = (const float*)d_in[7];
  const float* bhh2 = (const float*)d_in[8];
  float* out = (float*)d_out;

  dim3 grid(B_TOT / NB);  // 128 blocks x 16 batches
  dim3 block(BLOCK);      // 9 MFMA waves + 1 L2 wave
  hipLaunchKernelGGL(lstm2_kernel, grid, block, 0, stream,
                     x, Wih1, Whh1, bih1, bhh1, Wih2, Whh2, bih2, bhh2, out);
}